// Round 1
// 145.743 us; speedup vs baseline: 1.0141x; 1.0141x over previous
//
#include <hip/hip_runtime.h>
#include <hip/hip_bf16.h>
#include <stdint.h>

#define S_LEN 2048
#define D_DIM 1024
#define P_DIM 256
#define NQ_   8192
#define M_TOT 16384  // B*S

#define BM 32
#define BN 256
#define BK 64
#define CAP 32       // max span-endpoints per H row (lambda=2, P(>32)~1e-26)
#define HS  260      // padded f32 row stride for H tile in LDS (16B-aligned, bank-spread)

typedef __attribute__((ext_vector_type(4))) float  f32x4;
typedef __attribute__((ext_vector_type(8))) __bf16 bf16x8;

__device__ __forceinline__ void async16(const void* g, void* l) {
    __builtin_amdgcn_global_load_lds(
        (const __attribute__((address_space(1))) uint32_t*)g,
        (__attribute__((address_space(3))) uint32_t*)l, 16, 0, 0);
}

// ---------------- Kernel 0: W [1024][256] f32 -> WT [256][1024] bf16 ----------
// Also zeroes the 16384-entry row-bucket counters (first 16 blocks).
__global__ __launch_bounds__(1024) void wt_kernel(const float* __restrict__ W,
                                                  __bf16* __restrict__ WT,
                                                  int* __restrict__ cnt) {
    __shared__ __bf16 tile[32][33];
    const int k0 = blockIdx.x * 32;
    const int n0 = blockIdx.y * 32;
    const int tx = threadIdx.x, ty = threadIdx.y;
    const int g = (blockIdx.y * gridDim.x + blockIdx.x) * 1024 + ty * 32 + tx;
    if (g < M_TOT) cnt[g] = 0;
    tile[ty][tx] = (__bf16)W[(k0 + ty) * P_DIM + (n0 + tx)];
    __syncthreads();
    WT[(n0 + ty) * D_DIM + (k0 + tx)] = tile[tx][ty];
}

// ---------------- Kernel 1: inverted span index -------------------------------
// For each valid (q,set): endpoint rows get an entry (q<<2)|(set<<1)|half.
// Each dest slot in `out` is owned by exactly one entry -> atomic order moot.
__global__ __launch_bounds__(256) void index_build(const int* __restrict__ s1,
                                                   const int* __restrict__ e1,
                                                   const int* __restrict__ s2,
                                                   const int* __restrict__ e2,
                                                   const int* __restrict__ qb,
                                                   int* __restrict__ cnt,
                                                   int* __restrict__ bucket) {
    const int q = blockIdx.x * 256 + threadIdx.x;
    const int b = qb[q];
    int s = s1[q], e = e1[q];
    if (e >= s) {
        int r = b * S_LEN + s;
        int k = atomicAdd(&cnt[r], 1); if (k < CAP) bucket[r * CAP + k] = (q << 2);
        r = b * S_LEN + e;
        k = atomicAdd(&cnt[r], 1);     if (k < CAP) bucket[r * CAP + k] = (q << 2) | 1;
    }
    s = s2[q]; e = e2[q];
    if (e >= s) {
        int r = b * S_LEN + s;
        int k = atomicAdd(&cnt[r], 1); if (k < CAP) bucket[r * CAP + k] = (q << 2) | 2;
        r = b * S_LEN + e;
        k = atomicAdd(&cnt[r], 1);     if (k < CAP) bucket[r * CAP + k] = (q << 2) | 3;
    }
}

// ---------------- Kernel 2: zero invalid spans --------------------------------
// One 64-lane group per (q,set); invalid -> 512 f32 zeros (both halves).
__global__ __launch_bounds__(256) void invalid_zero(const int* __restrict__ s1,
                                                    const int* __restrict__ e1,
                                                    const int* __restrict__ s2,
                                                    const int* __restrict__ e2,
                                                    float* __restrict__ out) {
    const int grp  = threadIdx.x >> 6;
    const int gl   = threadIdx.x & 63;
    const int pair = blockIdx.x * 4 + grp;          // [0, 2*NQ)
    const int q    = pair & (NQ_ - 1);
    const int set  = pair >> 13;
    const int s = set ? s2[q] : s1[q];
    const int e = set ? e2[q] : e1[q];
    if (e >= s) return;
    const float4 z = make_float4(0.f, 0.f, 0.f, 0.f);
    float* dst = out + (size_t)set * (NQ_ * 512) + (size_t)q * 512;
    ((float4*)dst)[gl]      = z;
    ((float4*)dst)[gl + 64] = z;
}

// ---------------- Kernel 3: H = A @ W + b, fused span-scatter epilogue --------
// Main loop identical to the proven m97-style async GEMM. Epilogue: instead of
// writing H (16 MB HBM round-trip), stage the 32x256 tile (+bias) into the
// now-dead LDS, read this block's row buckets, and write each consumer's 1 KB
// slice straight to `out` (coalesced float4, 64 lanes/row, 4 rows in flight).
__global__ __launch_bounds__(256, 2) void gemm_kernel(const float*  __restrict__ A,
                                                      const __bf16* __restrict__ WT,
                                                      const float*  __restrict__ bias,
                                                      const int*    __restrict__ cnt,
                                                      const int*    __restrict__ bucket,
                                                      float*        __restrict__ out) {
    __shared__ __align__(16) char smem[2 * BM * BK * 2 + 2 * BN * BK * 2];  // 72 KB
    __shared__ int s_cnt[32];
    __shared__ int s_off[33];
    __shared__ int elist[32 * CAP];

    const int tid = threadIdx.x;
    const int w   = tid >> 6;
    const int l   = tid & 63;
    const int lm  = l & 15;
    const int q   = l >> 4;

    const int m0 = blockIdx.x * BM;

    auto bufA = [&](int buf) -> __bf16* { return (__bf16*)smem + buf * (BM * BK); };
    auto bufB = [&](int buf) -> __bf16* { return (__bf16*)(smem + 2 * BM * BK * 2) + buf * (BN * BK); };

    // ---- B async staging: inst j of wave w covers rows [r*8, r*8+8), r=w*8+j.
    // Lane l -> row r*8 + (l>>3), slot l&7 holds chunk c=(l&7)^((l>>3)&7).
    const int brow_l = l >> 3;
    const int bc     = (l & 7) ^ (brow_l & 7);

    auto stageB = [&](int buf, int k0) {
        __bf16* B = bufB(buf);
        #pragma unroll
        for (int j = 0; j < 8; ++j) {
            const int r   = w * 8 + j;
            const int row = r * 8 + brow_l;
            const __bf16* g = WT + (size_t)row * D_DIM + k0 + bc * 8;
            async16(g, B + r * 512);
        }
    };

    // ---- A staging: thread t -> row t>>3, slot t&7, chunk c=(t&7)^((t>>3)&7).
    const int arow = tid >> 3;
    const int acp  = tid & 7;
    const int ac   = acp ^ (arow & 7);
    const float* agp = A + (size_t)(m0 + arow) * D_DIM + ac * 8;

    float4 fa0, fa1;
    auto loadA = [&](int k0) {
        fa0 = *(const float4*)(agp + k0);
        fa1 = *(const float4*)(agp + k0 + 4);
    };
    auto writeA = [&](int buf) {
        bf16x8 v;
        v[0] = (__bf16)fa0.x; v[1] = (__bf16)fa0.y; v[2] = (__bf16)fa0.z; v[3] = (__bf16)fa0.w;
        v[4] = (__bf16)fa1.x; v[5] = (__bf16)fa1.y; v[6] = (__bf16)fa1.z; v[7] = (__bf16)fa1.w;
        *(bf16x8*)(bufA(buf) + arow * BK + acp * 8) = v;
    };

    f32x4 acc[2][4] = {};

    auto compute = [&](int buf) {
        const __bf16* Ab = bufA(buf);
        const __bf16* Bb = bufB(buf);
        #pragma unroll
        for (int kh = 0; kh < 2; ++kh) {
            const int pos = ((kh * 4 + q) ^ (lm & 7)) * 8;
            bf16x8 af[2], bfr[4];
            #pragma unroll
            for (int mi = 0; mi < 2; ++mi)
                af[mi] = *(const bf16x8*)(Ab + (mi * 16 + lm) * BK + pos);
            #pragma unroll
            for (int ni = 0; ni < 4; ++ni)
                bfr[ni] = *(const bf16x8*)(Bb + (w * 64 + ni * 16 + lm) * BK + pos);
            #pragma unroll
            for (int mi = 0; mi < 2; ++mi)
                #pragma unroll
                for (int ni = 0; ni < 4; ++ni)
                    acc[mi][ni] = __builtin_amdgcn_mfma_f32_16x16x32_bf16(
                        af[mi], bfr[ni], acc[mi][ni], 0, 0, 0);
        }
    };

    // ---- pipeline: 16 K-steps, buffers alternate 0,1,0,1,...
    loadA(0);
    stageB(0, 0);
    writeA(0);
    __syncthreads();

    #pragma unroll 1
    for (int p = 0; p < 7; ++p) {
        const int k1 = (2 * p + 1) * BK, k2 = (2 * p + 2) * BK;
        loadA(k1); stageB(1, k1);
        __builtin_amdgcn_sched_barrier(0);
        compute(0);
        __builtin_amdgcn_sched_barrier(0);
        writeA(1);
        __syncthreads();
        loadA(k2); stageB(0, k2);
        __builtin_amdgcn_sched_barrier(0);
        compute(1);
        __builtin_amdgcn_sched_barrier(0);
        writeA(0);
        __syncthreads();
    }
    {   // step 14 (buf 0) while staging step 15 (buf 1)
        const int k1 = 15 * BK;
        loadA(k1); stageB(1, k1);
        __builtin_amdgcn_sched_barrier(0);
        compute(0);
        __builtin_amdgcn_sched_barrier(0);
        writeA(1);
        __syncthreads();
    }
    compute(1);

    // ---- fused epilogue ------------------------------------------------------
    __syncthreads();                       // all waves done reading As/Bs
    float* hs = (float*)smem;              // 32 x HS f32 overlay (33.3 KB < 72 KB)

    if (tid < 32) { int c = cnt[m0 + tid]; s_cnt[tid] = c < CAP ? c : CAP; }

    // D layout: row = mi*16 + q*4 + r, col = w*64 + ni*16 + lm
    #pragma unroll
    for (int ni = 0; ni < 4; ++ni) {
        const int col = w * 64 + ni * 16 + lm;
        const float bv = bias[col];
        #pragma unroll
        for (int mi = 0; mi < 2; ++mi) {
            const int rbase = mi * 16 + q * 4;
            #pragma unroll
            for (int r = 0; r < 4; ++r)
                hs[(rbase + r) * HS + col] = acc[mi][ni][r] + bv;
        }
    }
    __syncthreads();
    if (tid == 0) {
        int a = 0;
        #pragma unroll 1
        for (int i = 0; i < 32; ++i) { s_off[i] = a; a += s_cnt[i]; }
        s_off[32] = a;
    }
    __syncthreads();
    if (tid < 32) {
        const int o = s_off[tid], c = s_cnt[tid];
        const int* bk = bucket + (size_t)(m0 + tid) * CAP;
        for (int k = 0; k < c; ++k)
            elist[o + k] = (tid << 15) | (bk[k] & 0x7fff);
    }
    __syncthreads();

    const int E   = s_off[32];
    const int grp = tid >> 6;
    const int gl  = tid & 63;
    #pragma unroll 1
    for (int j = grp; j < E; j += 4) {
        const int ent  = elist[j];
        const int rl   = ent >> 15;
        const int code = ent & 0x7fff;
        const int qq   = code >> 2;
        const int st   = (code >> 1) & 1;
        const int hf   = code & 1;
        const float4 v = *(const float4*)&hs[rl * HS + gl * 4];
        *(float4*)(out + (size_t)st * (NQ_ * 512) + (size_t)qq * 512 + hf * 256 + gl * 4) = v;
    }
}

// ---------------- launch ------------------------------------------------------
extern "C" void kernel_launch(void* const* d_in, const int* in_sizes, int n_in,
                              void* d_out, int out_size, void* d_ws, size_t ws_size,
                              hipStream_t stream) {
    const float* A    = (const float*)d_in[1];
    const int*   s1   = (const int*)  d_in[2];
    const int*   e1   = (const int*)  d_in[3];
    const int*   qb   = (const int*)  d_in[4];
    const int*   s2   = (const int*)  d_in[5];
    const int*   e2   = (const int*)  d_in[6];
    const float* W    = (const float*)d_in[7];
    const float* bias = (const float*)d_in[8];
    float*       out  = (float*)d_out;

    __bf16* WT     = (__bf16*)d_ws;                                   // 512 KB
    int*    cnt    = (int*)((char*)d_ws + (1 << 20));                 // 64 KB
    int*    bucket = (int*)((char*)d_ws + (1 << 20) + (1 << 16));     // 2 MB

    wt_kernel    <<<dim3(32, 8), dim3(32, 32), 0, stream>>>(W, WT, cnt);
    index_build  <<<dim3(NQ_ / 256), dim3(256), 0, stream>>>(s1, e1, s2, e2, qb, cnt, bucket);
    invalid_zero <<<dim3(2 * NQ_ / 4), dim3(256), 0, stream>>>(s1, e1, s2, e2, out);
    gemm_kernel  <<<dim3(M_TOT / BM), dim3(256), 0, stream>>>(A, WT, bias, cnt, bucket, out);
}